// Round 4
// baseline (196.410 us; speedup 1.0000x reference)
//
#include <hip/hip_runtime.h>
#include <hip/hip_bf16.h>
#include <stdint.h>

typedef short bf16x8 __attribute__((ext_vector_type(8)));
typedef float f32x4  __attribute__((ext_vector_type(4)));
typedef float f32x16 __attribute__((ext_vector_type(16)));
typedef unsigned int u32;

#define N_SP 4096
// 8^-0.5 * log2(e): fold softmax scale + exp->exp2 conversion into Q weights/bias
#define QSCALE 0.5100697284f

__device__ inline unsigned short f2bf(float f) {
    unsigned u = __float_as_uint(f);
    u += 0x7fff + ((u >> 16) & 1);
    return (unsigned short)(u >> 16);
}
__device__ inline u32 cvtpk_bf16(float lo, float hi) {
    u32 r;
    asm("v_cvt_pk_bf16_f32 %0, %1, %2" : "=v"(r) : "v"(lo), "v"(hi));
    return r;
}
__device__ inline void pl32swap(u32& a, u32& b) {
    asm volatile("v_permlane32_swap_b32 %0, %1" : "+v"(a), "+v"(b));
}
__device__ inline void gl_lds16(const void* g, void* l) {
    __builtin_amdgcn_global_load_lds(
        (const __attribute__((address_space(1))) unsigned int*)g,
        (__attribute__((address_space(3))) unsigned int*)l, 16, 0, 0);
}

union U { u32 w[4]; bf16x8 v; };

// Workspace layouts (bf16), per br (br = b*2 + branch):
//  Q: [qt][chunk l][8]  chunk l -> B-frag lane l: Q[d=(l>>5)*8+j][q=l&31]
//  K: [nt][chunk l][8]  chunk l -> A-frag lane l: K[key=l&31][d=(l>>5)*8+j]
//  V: [nt][(kt*2+ct)*512 + l*8 + j] -> A-frag lane l: V[c=ct*32+(l&31)][key=kt*16+(l>>5)*8+j]

// ---------------- Stage 1: fused QKV projection into fragment-layout buffers ---------
__global__ __launch_bounds__(256) void stage1_kernel(
    const float* __restrict__ in1, const float* __restrict__ in2,
    const float* __restrict__ wq1, const float* __restrict__ bq1,
    const float* __restrict__ wq2, const float* __restrict__ bq2,
    const float* __restrict__ wq3, const float* __restrict__ bq3,
    const float* __restrict__ wq4, const float* __restrict__ bq4,
    const float* __restrict__ wk,  const float* __restrict__ bk,
    const float* __restrict__ wv,  const float* __restrict__ bv,
    const float* __restrict__ wk2, const float* __restrict__ bk2,
    const float* __restrict__ wv2, const float* __restrict__ bv2,
    unsigned short* __restrict__ Qs, unsigned short* __restrict__ Ks,
    unsigned short* __restrict__ Vs)
{
    __shared__ float w1f[16][64];   // effective q weight on input1 (scaled)
    __shared__ float w2f[16][64];   // effective q weight on input2 (scaled)
    __shared__ float wkf[16][64];
    __shared__ float wvf[64][64];
    __shared__ float qb[16], kbb[16], vbb[64];

    const int bid = blockIdx.x;
    const int br = bid & 7;          // XCD affinity (stage1+attn use the same mapping)
    const int ntl = bid >> 3;        // 0..127, 32 n per block
    const int b = br >> 1, rr = br & 1;
    const int tid = threadIdx.x;

    // q_in1 = [q1, q3, q4, q2]; q_in2 = [q2, q4, q3, q1]
    // i3 = (2/3)i1 + (1/3)i2 ; i4 = (1/3)i1 + (2/3)i2
    const float* wqs[4]; const float* bqs[4]; float c1s[4], c2s[4];
    if (rr == 0) {
        wqs[0]=wq1; bqs[0]=bq1; c1s[0]=1.f;       c2s[0]=0.f;
        wqs[1]=wq3; bqs[1]=bq3; c1s[1]=2.f/3.f;   c2s[1]=1.f/3.f;
        wqs[2]=wq4; bqs[2]=bq4; c1s[2]=1.f/3.f;   c2s[2]=2.f/3.f;
        wqs[3]=wq2; bqs[3]=bq2; c1s[3]=0.f;       c2s[3]=1.f;
    } else {
        wqs[0]=wq2; bqs[0]=bq2; c1s[0]=0.f;       c2s[0]=1.f;
        wqs[1]=wq4; bqs[1]=bq4; c1s[1]=1.f/3.f;   c2s[1]=2.f/3.f;
        wqs[2]=wq3; bqs[2]=bq3; c1s[2]=2.f/3.f;   c2s[2]=1.f/3.f;
        wqs[3]=wq1; bqs[3]=bq1; c1s[3]=1.f;       c2s[3]=0.f;
    }
    const float* wkp = rr ? wk2 : wk;  const float* bkp = rr ? bk2 : bk;
    const float* wvp = rr ? wv2 : wv;  const float* bvp = rr ? bv2 : bv;

    for (int e = tid; e < 1024; e += 256) {
        int g = e >> 8;
        int h = e >> 6;
        int ch = e & 63;
        float wq_ = wqs[g][e & 255];
        w1f[h][ch] = c1s[g] * wq_ * QSCALE;
        w2f[h][ch] = c2s[g] * wq_ * QSCALE;
        wkf[h][ch] = wkp[e];
    }
    for (int e = tid; e < 4096; e += 256) wvf[e >> 6][e & 63] = wvp[e];
    if (tid < 16) { qb[tid] = bqs[tid >> 2][tid & 3] * QSCALE; kbb[tid] = bkp[tid]; }
    if (tid < 64) vbb[tid] = bvp[tid];
    __syncthreads();

    const int nl = tid & 31;         // n within tile
    const int og = tid >> 5;         // output group 0..7 (wave-uniform per half-wave)
    const int n = ntl * 32 + nl;
    const float* x1p = in1 + (size_t)b * 64 * N_SP + n;
    const float* x2p = in2 + (size_t)b * 64 * N_SP + n;
    const float* xfp = rr ? x2p : x1p;

    if (og < 2) {
        // q outputs d = og*8 .. og*8+7  (needs both inputs)
        float acc[8];
        #pragma unroll
        for (int o = 0; o < 8; o++) acc[o] = qb[og * 8 + o];
        for (int g = 0; g < 8; g++) {
            float x1v[8], x2v[8];
            #pragma unroll
            for (int cc = 0; cc < 8; cc++) {
                x1v[cc] = x1p[(size_t)(g * 8 + cc) * N_SP];
                x2v[cc] = x2p[(size_t)(g * 8 + cc) * N_SP];
            }
            #pragma unroll
            for (int o = 0; o < 8; o++) {
                const f32x4* w1p = (const f32x4*)&w1f[og * 8 + o][g * 8];
                const f32x4* w2p = (const f32x4*)&w2f[og * 8 + o][g * 8];
                f32x4 wa = w1p[0], wb = w1p[1], wc = w2p[0], wd = w2p[1];
                #pragma unroll
                for (int cc = 0; cc < 4; cc++) {
                    acc[o] += wa[cc] * x1v[cc]     + wc[cc] * x2v[cc];
                    acc[o] += wb[cc] * x1v[4 + cc] + wd[cc] * x2v[4 + cc];
                }
            }
        }
        bf16x8 qv;
        #pragma unroll
        for (int o = 0; o < 8; o++) qv[o] = (short)f2bf(acc[o]);
        *(bf16x8*)(Qs + (size_t)br * 65536 + ntl * 512 + og * 256 + nl * 8) = qv;
    } else if (og < 4) {
        // k outputs d = (og-2)*8 .. +7
        const int dg = og - 2;
        float acc[8];
        #pragma unroll
        for (int o = 0; o < 8; o++) acc[o] = kbb[dg * 8 + o];
        for (int g = 0; g < 8; g++) {
            float xfv[8];
            #pragma unroll
            for (int cc = 0; cc < 8; cc++) xfv[cc] = xfp[(size_t)(g * 8 + cc) * N_SP];
            #pragma unroll
            for (int o = 0; o < 8; o++) {
                const f32x4* wkq = (const f32x4*)&wkf[dg * 8 + o][g * 8];
                f32x4 wa = wkq[0], wb = wkq[1];
                #pragma unroll
                for (int cc = 0; cc < 4; cc++) {
                    acc[o] += wa[cc] * xfv[cc];
                    acc[o] += wb[cc] * xfv[4 + cc];
                }
            }
        }
        bf16x8 kv;
        #pragma unroll
        for (int o = 0; o < 8; o++) kv[o] = (short)f2bf(acc[o]);
        // K A-frag layout: chunk = dg*32 + key
        *(bf16x8*)(Ks + (size_t)br * 65536 + ntl * 512 + dg * 256 + nl * 8) = kv;
    } else {
        // v outputs c = (og-4)*16 .. +15
        const int cg = og - 4;
        float acc[16];
        #pragma unroll
        for (int j = 0; j < 16; j++) acc[j] = vbb[cg * 16 + j];
        for (int g = 0; g < 8; g++) {
            float xfv[8];
            #pragma unroll
            for (int cc = 0; cc < 8; cc++) xfv[cc] = xfp[(size_t)(g * 8 + cc) * N_SP];
            #pragma unroll
            for (int j = 0; j < 16; j++) {
                const f32x4* wvq = (const f32x4*)&wvf[cg * 16 + j][g * 8];
                f32x4 wa = wvq[0], wb = wvq[1];
                #pragma unroll
                for (int cc = 0; cc < 4; cc++) {
                    acc[j] += wa[cc] * xfv[cc];
                    acc[j] += wb[cc] * xfv[4 + cc];
                }
            }
        }
        // V A-frag layout: [(kt*2+ct)*512 + (hi*32+c31)*8 + j]
        const int key5 = n & 31, kt = key5 >> 4, keyr = key5 & 15;
        const int hi_ = keyr >> 3, j_ = keyr & 7;
        size_t vbase = (size_t)br * 262144 + (size_t)(n >> 5) * 2048 +
                       (size_t)hi_ * 256 + j_;
        #pragma unroll
        for (int j = 0; j < 16; j++) {
            int c = cg * 16 + j;
            Vs[vbase + (size_t)((kt * 2 + (c >> 5)) * 512 + (c & 31) * 8)] = f2bf(acc[j]);
        }
    }
}

// ---------------- Stage 2: 4 waves share staged K/V tiles; wave-complete softmax -----
#define STAGE(T) do {                                                          \
    int nt_ = (T); int bi_ = nt_ & 3;                                          \
    gl_lds16(Vb + (size_t)nt_ * 2048 + tid * 8, &lsV[bi_][tid * 8]);           \
    if (w == 0) gl_lds16(Kb + (size_t)nt_ * 512 + l * 8, &lsK[bi_][l * 8]);    \
} while (0)

#define FRAG_READ(S, BI) do {                                                  \
    int bi_ = (BI);                                                            \
    const short* kp_ = &lsK[bi_][l * 8];                                       \
    const short* vp_ = &lsV[bi_][l * 8];                                       \
    fk##S  = *(const bf16x8*)kp_;                                              \
    fv0##S = *(const bf16x8*)(vp_);                                            \
    fv1##S = *(const bf16x8*)(vp_ + 512);                                      \
    fv2##S = *(const bf16x8*)(vp_ + 1024);                                     \
    fv3##S = *(const bf16x8*)(vp_ + 1536);                                     \
} while (0)

#define COMPUTE(S) do {                                                        \
    f32x16 s_ = __builtin_amdgcn_mfma_f32_32x32x16_bf16(fk##S, aq, z16, 0, 0, 0); \
    float p_[16];                                                              \
    _Pragma("unroll")                                                          \
    for (int r_ = 0; r_ < 16; ++r_) p_[r_] = __builtin_amdgcn_exp2f(s_[r_]);   \
    u32 a0 = cvtpk_bf16(p_[0], p_[1]),  a2 = cvtpk_bf16(p_[4], p_[5]);         \
    pl32swap(a0, a2);                                                          \
    u32 a1 = cvtpk_bf16(p_[2], p_[3]),  a3 = cvtpk_bf16(p_[6], p_[7]);         \
    pl32swap(a1, a3);                                                          \
    u32 c0 = cvtpk_bf16(p_[8], p_[9]),  c2 = cvtpk_bf16(p_[12], p_[13]);       \
    pl32swap(c0, c2);                                                          \
    u32 c1 = cvtpk_bf16(p_[10], p_[11]), c3 = cvtpk_bf16(p_[14], p_[15]);      \
    pl32swap(c1, c3);                                                          \
    U u0_, u1_;                                                                \
    u0_.w[0] = a0; u0_.w[1] = a1; u0_.w[2] = a2; u0_.w[3] = a3;                \
    u1_.w[0] = c0; u1_.w[1] = c1; u1_.w[2] = c2; u1_.w[3] = c3;                \
    acc0 = __builtin_amdgcn_mfma_f32_32x32x16_bf16(fv0##S, u0_.v, acc0, 0, 0, 0); \
    acc1 = __builtin_amdgcn_mfma_f32_32x32x16_bf16(fv1##S, u0_.v, acc1, 0, 0, 0); \
    acc0 = __builtin_amdgcn_mfma_f32_32x32x16_bf16(fv2##S, u1_.v, acc0, 0, 0, 0); \
    acc1 = __builtin_amdgcn_mfma_f32_32x32x16_bf16(fv3##S, u1_.v, acc1, 0, 0, 0); \
    accR = __builtin_amdgcn_mfma_f32_32x32x16_bf16(ones, u0_.v, accR, 0, 0, 0);   \
    accR = __builtin_amdgcn_mfma_f32_32x32x16_bf16(ones, u1_.v, accR, 0, 0, 0);   \
} while (0)

#define SYNC(TT) do {                                                          \
    if ((TT) < 125) {                                                          \
        if (w == 0) asm volatile("s_waitcnt vmcnt(2) lgkmcnt(0)" ::: "memory");\
        else        asm volatile("s_waitcnt vmcnt(1) lgkmcnt(0)" ::: "memory");\
    } else {                                                                   \
        asm volatile("s_waitcnt vmcnt(0) lgkmcnt(0)" ::: "memory");            \
    }                                                                          \
    __builtin_amdgcn_s_barrier();                                              \
} while (0)

__global__ __launch_bounds__(256, 1) void attn_kernel(
    const unsigned short* __restrict__ Qs, const unsigned short* __restrict__ Ks,
    const unsigned short* __restrict__ Vs,
    const float* __restrict__ in1, const float* __restrict__ in2,
    const float* __restrict__ gamma_p, float* __restrict__ out)
{
    __shared__ short lsK[4][512];    // 4-deep K tile buffers (32 key x 16 d)
    __shared__ short lsV[4][2048];   // 4-deep V tile buffers (32 key x 64 c)

    const int bid = blockIdx.x;
    const int br = bid & 7;          // XCD affinity
    const int qtg = bid >> 3;        // 0..31
    const int b = br >> 1, rr = br & 1;
    const int tid = threadIdx.x;
    const int w = tid >> 6;          // wave 0..3, one 32-q tile each
    const int l = tid & 63;
    const int q31 = l & 31, hi = l >> 5;
    const int qt = qtg * 4 + w;      // 0..127

    const unsigned short* Qb = Qs + (size_t)br * 65536;
    const unsigned short* Kb = Ks + (size_t)br * 65536;
    const unsigned short* Vb = Vs + (size_t)br * 262144;

    const bf16x8 aq = *(const bf16x8*)(Qb + qt * 512 + l * 8);   // Q B-frag
    bf16x8 ones;
    #pragma unroll
    for (int j = 0; j < 8; j++) ones[j] = (short)0x3F80;         // bf16 1.0
    const f32x16 z16 = {0,0,0,0,0,0,0,0,0,0,0,0,0,0,0,0};

    f32x16 acc0 = z16;   // O[c=0..31][q]
    f32x16 acc1 = z16;   // O[c=32..63][q]
    f32x16 accR = z16;   // row sums (all regs identical)

    bf16x8 fk0, fv00, fv10, fv20, fv30;
    bf16x8 fk1, fv01, fv11, fv21, fv31;

    // prologue: stage tiles 0,1,2 (depth-3); wait for 0,1; leave 2 in flight
    STAGE(0); STAGE(1); STAGE(2);
    if (w == 0) asm volatile("s_waitcnt vmcnt(2)" ::: "memory");
    else        asm volatile("s_waitcnt vmcnt(1)" ::: "memory");
    __builtin_amdgcn_s_barrier();
    FRAG_READ(0, 0);

    for (int t = 0; t < 128; t += 2) {
        if (t + 3 < 128) STAGE(t + 3);
        FRAG_READ(1, (t + 1) & 3);
        COMPUTE(0);
        SYNC(t);
        if (t + 4 < 128) STAGE(t + 4);
        if (t + 2 < 128) FRAG_READ(0, (t + 2) & 3);
        COMPUTE(1);
        if (t + 2 < 128) SYNC(t + 1);
    }

    // epilogue: purely per-lane normalization; coalesced register stores
    const float g = gamma_p[0];
    const float inv = 1.0f / accR[0];
    const float* featp = (rr ? in2 : in1) + (size_t)b * 64 * N_SP;
    float* outp = out + (size_t)rr * (4ull * 64 * N_SP) + (size_t)b * 64 * N_SP;
    const int m = qt * 32 + q31;

    #pragma unroll
    for (int r = 0; r < 16; r++) {
        int c = (r & 3) + 8 * (r >> 2) + 4 * hi;
        size_t o1 = (size_t)c * N_SP + m;
        size_t o2 = (size_t)(c + 32) * N_SP + m;
        outp[o1] = g * (acc0[r] * inv) + featp[o1];
        outp[o2] = g * (acc1[r] * inv) + featp[o2];
    }
}

extern "C" void kernel_launch(void* const* d_in, const int* in_sizes, int n_in,
                              void* d_out, int out_size, void* d_ws, size_t ws_size,
                              hipStream_t stream) {
    const float* in1 = (const float*)d_in[0];
    const float* in2 = (const float*)d_in[1];
    const float* wq1 = (const float*)d_in[2];  const float* bq1 = (const float*)d_in[3];
    const float* wq2 = (const float*)d_in[4];  const float* bq2 = (const float*)d_in[5];
    const float* wq3 = (const float*)d_in[6];  const float* bq3 = (const float*)d_in[7];
    const float* wq4 = (const float*)d_in[8];  const float* bq4 = (const float*)d_in[9];
    const float* wk  = (const float*)d_in[10]; const float* bk  = (const float*)d_in[11];
    const float* wv  = (const float*)d_in[12]; const float* bv  = (const float*)d_in[13];
    const float* wk2 = (const float*)d_in[14]; const float* bk2 = (const float*)d_in[15];
    const float* wv2 = (const float*)d_in[16]; const float* bv2 = (const float*)d_in[17];
    const float* gamma_p = (const float*)d_in[18];

    unsigned short* Qs = (unsigned short*)d_ws;          // 8 * 65536 shorts
    unsigned short* Ks = Qs + (size_t)8 * 65536;         // 8 * 65536 shorts
    unsigned short* Vs = Ks + (size_t)8 * 65536;         // 8 * 262144 shorts

    stage1_kernel<<<dim3(1024), 256, 0, stream>>>(in1, in2, wq1, bq1, wq2, bq2,
                                                  wq3, bq3, wq4, bq4, wk, bk, wv, bv,
                                                  wk2, bk2, wv2, bv2, Qs, Ks, Vs);
    attn_kernel<<<dim3(256), 256, 0, stream>>>(Qs, Ks, Vs, in1, in2, gamma_p,
                                               (float*)d_out);
}

// Round 5
// 176.726 us; speedup vs baseline: 1.1114x; 1.1114x over previous
//
#include <hip/hip_runtime.h>
#include <hip/hip_bf16.h>
#include <stdint.h>

typedef short bf16x8 __attribute__((ext_vector_type(8)));
typedef float f32x4  __attribute__((ext_vector_type(4)));
typedef float f32x16 __attribute__((ext_vector_type(16)));
typedef unsigned int u32;

#define N_SP 4096
// 8^-0.5 * log2(e): fold softmax scale + exp->exp2 conversion into Q
#define QSCALE 0.5100697284f

__device__ inline unsigned short f2bf(float f) {
    unsigned u = __float_as_uint(f);
    u += 0x7fff + ((u >> 16) & 1);
    return (unsigned short)(u >> 16);
}
__device__ inline u32 cvtpk_bf16(float lo, float hi) {
    u32 r;
    asm("v_cvt_pk_bf16_f32 %0, %1, %2" : "=v"(r) : "v"(lo), "v"(hi));
    return r;
}
__device__ inline void pl32swap(u32& a, u32& b) {
    asm volatile("v_permlane32_swap_b32 %0, %1" : "+v"(a), "+v"(b));
}

union U { u32 w[4]; bf16x8 v; };

// Workspace layouts (bf16), per br (br = b*2 + branch):
//  Q: [qt][l*8+j] -> B-frag lane l: Q[d=(l>>5)*8+j][q=l&31]
//  K: [nt][l*8+j] -> A-frag lane l: K[key=l&31][d=(l>>5)*8+j]
//  V: [nt][(kt*2+ct)*512 + l*8 + j] -> B-frag lane l: V[key=kt*16+(l>>5)*8+j][c=ct*32+(l&31)]

// ---------------- Stage 1: QKV projection; weights via scalar loads (SGPR) ----------
__global__ __launch_bounds__(512, 4) void stage1_kernel(
    const float* __restrict__ in1, const float* __restrict__ in2,
    const float* __restrict__ wq1, const float* __restrict__ bq1,
    const float* __restrict__ wq2, const float* __restrict__ bq2,
    const float* __restrict__ wq3, const float* __restrict__ bq3,
    const float* __restrict__ wq4, const float* __restrict__ bq4,
    const float* __restrict__ wk,  const float* __restrict__ bk,
    const float* __restrict__ wv,  const float* __restrict__ bv,
    const float* __restrict__ wk2, const float* __restrict__ bk2,
    const float* __restrict__ wv2, const float* __restrict__ bv2,
    unsigned short* __restrict__ Qs, unsigned short* __restrict__ Ks,
    unsigned short* __restrict__ Vs)
{
    const int bid = blockIdx.x;        // 512 blocks = 8 br x 64 ntl
    const int br = bid & 7;            // XCD affinity
    const int ntl = bid >> 3;          // 0..63 (64 n per block)
    const int b = br >> 1, rr = br & 1;
    const int tid = threadIdx.x;
    const int og = tid >> 6;           // wave id 0..7 (wave-uniform!)
    const int nl = tid & 63;
    const int n = ntl * 64 + nl;
    const int nt = n >> 5, nl32 = n & 31;

    const float* x1p = in1 + (size_t)b * 64 * N_SP + n;
    const float* x2p = in2 + (size_t)b * 64 * N_SP + n;
    const float* xfp = rr ? x2p : x1p;

    // q_in1 = [q1, q3, q4, q2]; q_in2 = [q2, q4, q3, q1]
    // i3 = (2/3)i1 + (1/3)i2 ; i4 = (1/3)i1 + (2/3)i2
    const float* wqs[4]; const float* bqs[4]; float c1s[4], c2s[4];
    if (rr == 0) {
        wqs[0]=wq1; bqs[0]=bq1; c1s[0]=1.f;       c2s[0]=0.f;
        wqs[1]=wq3; bqs[1]=bq3; c1s[1]=2.f/3.f;   c2s[1]=1.f/3.f;
        wqs[2]=wq4; bqs[2]=bq4; c1s[2]=1.f/3.f;   c2s[2]=2.f/3.f;
        wqs[3]=wq2; bqs[3]=bq2; c1s[3]=0.f;       c2s[3]=1.f;
    } else {
        wqs[0]=wq2; bqs[0]=bq2; c1s[0]=0.f;       c2s[0]=1.f;
        wqs[1]=wq4; bqs[1]=bq4; c1s[1]=1.f/3.f;   c2s[1]=2.f/3.f;
        wqs[2]=wq3; bqs[2]=bq3; c1s[2]=2.f/3.f;   c2s[2]=1.f/3.f;
        wqs[3]=wq1; bqs[3]=bq1; c1s[3]=1.f;       c2s[3]=0.f;
    }
    const float* wkp = rr ? wk2 : wk;  const float* bkp = rr ? bk2 : bk;
    const float* wvp = rr ? wv2 : wv;  const float* bvp = rr ? bv2 : bv;

    if (og < 2) {
        // Q channels d = og*8 .. +7  (= weight groups gA, gB; xmix factoring)
        const int gA = og * 2, gB = og * 2 + 1;
        const float* wA = wqs[gA]; const float* wB = wqs[gB];
        const float c1A = c1s[gA], c2A = c2s[gA];
        const float c1B = c1s[gB], c2B = c2s[gB];
        float acc[8];
        #pragma unroll
        for (int o = 0; o < 8; o++) acc[o] = 0.f;
        #pragma unroll
        for (int half = 0; half < 2; half++) {
            float xa[32], xb[32];
            #pragma unroll
            for (int cc = 0; cc < 32; cc++) {
                float x1 = x1p[(size_t)(half * 32 + cc) * N_SP];
                float x2 = x2p[(size_t)(half * 32 + cc) * N_SP];
                xa[cc] = c1A * x1 + c2A * x2;
                xb[cc] = c1B * x1 + c2B * x2;
            }
            #pragma unroll
            for (int o = 0; o < 4; o++) {
                #pragma unroll
                for (int cc = 0; cc < 32; cc++) {
                    acc[o]     += wA[o * 64 + half * 32 + cc] * xa[cc];
                    acc[4 + o] += wB[o * 64 + half * 32 + cc] * xb[cc];
                }
            }
        }
        bf16x8 qv;
        #pragma unroll
        for (int o = 0; o < 8; o++) {
            float bias = (o < 4) ? bqs[gA][o] : bqs[gB][o - 4];
            qv[o] = (short)f2bf((acc[o] + bias) * QSCALE);
        }
        *(bf16x8*)(Qs + (size_t)br * 65536 + nt * 512 + og * 256 + nl32 * 8) = qv;
    } else if (og < 4) {
        // K channels d = dg*8 .. +7
        const int dg = og - 2;
        float acc[8];
        #pragma unroll
        for (int o = 0; o < 8; o++) acc[o] = 0.f;
        #pragma unroll
        for (int half = 0; half < 2; half++) {
            float xf[32];
            #pragma unroll
            for (int cc = 0; cc < 32; cc++) xf[cc] = xfp[(size_t)(half * 32 + cc) * N_SP];
            #pragma unroll
            for (int o = 0; o < 8; o++) {
                #pragma unroll
                for (int cc = 0; cc < 32; cc++)
                    acc[o] += wkp[(dg * 8 + o) * 64 + half * 32 + cc] * xf[cc];
            }
        }
        bf16x8 kv;
        #pragma unroll
        for (int o = 0; o < 8; o++) kv[o] = (short)f2bf(acc[o] + bkp[dg * 8 + o]);
        *(bf16x8*)(Ks + (size_t)br * 65536 + nt * 512 + dg * 256 + nl32 * 8) = kv;
    } else {
        // V channels c = cg*16 .. +15
        const int cg = og - 4;
        float acc[16];
        #pragma unroll
        for (int o = 0; o < 16; o++) acc[o] = 0.f;
        #pragma unroll
        for (int half = 0; half < 2; half++) {
            float xf[32];
            #pragma unroll
            for (int cc = 0; cc < 32; cc++) xf[cc] = xfp[(size_t)(half * 32 + cc) * N_SP];
            #pragma unroll
            for (int o = 0; o < 16; o++) {
                #pragma unroll
                for (int cc = 0; cc < 32; cc++)
                    acc[o] += wvp[(cg * 16 + o) * 64 + half * 32 + cc] * xf[cc];
            }
        }
        const int kt = (n >> 4) & 1;
        size_t vb = (size_t)br * 262144 + (size_t)nt * 2048 +
                    (size_t)((n >> 3) & 1) * 256 + (n & 7);
        #pragma unroll
        for (int o = 0; o < 16; o++) {
            int c = cg * 16 + o;
            Vs[vb + (size_t)((kt * 2 + (c >> 5)) * 512 + (c & 31) * 8)] =
                f2bf(acc[o] + bvp[c]);
        }
    }
}

// ---------------- Stage 2: q-QUAD waves, key-split 8, in-register softmax ------------
#define SOFTPV(QT, ACCA, ACCB) do {                                               \
    f32x16 s_ = __builtin_amdgcn_mfma_f32_32x32x16_bf16(kfA, aq##QT, z16, 0, 0, 0); \
    float p_[16];                                                                 \
    _Pragma("unroll")                                                             \
    for (int r_ = 0; r_ < 16; ++r_) p_[r_] = __builtin_amdgcn_exp2f(s_[r_]);      \
    rsum##QT += (((p_[0]+p_[1])+(p_[2]+p_[3]))+((p_[4]+p_[5])+(p_[6]+p_[7])))     \
              + (((p_[8]+p_[9])+(p_[10]+p_[11]))+((p_[12]+p_[13])+(p_[14]+p_[15]))); \
    u32 a0 = cvtpk_bf16(p_[0], p_[1]),  a2 = cvtpk_bf16(p_[4], p_[5]);            \
    pl32swap(a0, a2);                                                             \
    u32 a1 = cvtpk_bf16(p_[2], p_[3]),  a3 = cvtpk_bf16(p_[6], p_[7]);            \
    pl32swap(a1, a3);                                                             \
    u32 c0 = cvtpk_bf16(p_[8], p_[9]),  c2 = cvtpk_bf16(p_[12], p_[13]);          \
    pl32swap(c0, c2);                                                             \
    u32 c1 = cvtpk_bf16(p_[10], p_[11]), c3 = cvtpk_bf16(p_[14], p_[15]);         \
    pl32swap(c1, c3);                                                             \
    U u0_, u1_;                                                                   \
    u0_.w[0]=a0; u0_.w[1]=a1; u0_.w[2]=a2; u0_.w[3]=a3;                           \
    u1_.w[0]=c0; u1_.w[1]=c1; u1_.w[2]=c2; u1_.w[3]=c3;                           \
    ACCA = __builtin_amdgcn_mfma_f32_32x32x16_bf16(u0_.v, vf0, ACCA, 0, 0, 0);    \
    ACCB = __builtin_amdgcn_mfma_f32_32x32x16_bf16(u0_.v, vf1, ACCB, 0, 0, 0);    \
    ACCA = __builtin_amdgcn_mfma_f32_32x32x16_bf16(u1_.v, vf2, ACCA, 0, 0, 0);    \
    ACCB = __builtin_amdgcn_mfma_f32_32x32x16_bf16(u1_.v, vf3, ACCB, 0, 0, 0);    \
} while (0)

#define EPI(QT, ACCA, ACCB) do {                                                  \
    float rs_ = rsum##QT + __shfl_xor(rsum##QT, 32, 64);                          \
    if (l < 32) rsl[w][l] = rs_;                                                  \
    _Pragma("unroll")                                                             \
    for (int r_ = 0; r_ < 16; ++r_) {                                             \
        int qrow_ = (r_ & 3) + 8 * (r_ >> 2) + 4 * hi;                            \
        accb[w][q31][qrow_]      = ACCA[r_];                                      \
        accb[w][32 + q31][qrow_] = ACCB[r_];                                      \
    }                                                                             \
    __syncthreads();                                                              \
    if (tid < 32) invl[tid] = 1.0f /                                              \
        (((rsl[0][tid]+rsl[1][tid])+(rsl[2][tid]+rsl[3][tid])) +                  \
         ((rsl[4][tid]+rsl[5][tid])+(rsl[6][tid]+rsl[7][tid])));                  \
    __syncthreads();                                                              \
    {                                                                             \
        const int c_ = tid >> 3, mg_ = tid & 7;                                   \
        const int m_ = qq * 128 + (QT) * 32 + mg_ * 4;                            \
        f32x4 o_;                                                                 \
        _Pragma("unroll")                                                         \
        for (int mi_ = 0; mi_ < 4; ++mi_) {                                       \
            int q_ = mg_ * 4 + mi_;                                               \
            float v_ = ((accb[0][c_][q_]+accb[1][c_][q_])+(accb[2][c_][q_]+accb[3][c_][q_])) \
                     + ((accb[4][c_][q_]+accb[5][c_][q_])+(accb[6][c_][q_]+accb[7][c_][q_])); \
            o_[mi_] = g * (v_ * invl[q_]) + featp[(size_t)c_ * N_SP + m_ + mi_];  \
        }                                                                         \
        *(f32x4*)(outp + (size_t)c_ * N_SP + m_) = o_;                            \
    }                                                                             \
    __syncthreads();                                                              \
} while (0)

__global__ __launch_bounds__(512, 2) void attn_kernel(
    const unsigned short* __restrict__ Qs, const unsigned short* __restrict__ Ks,
    const unsigned short* __restrict__ Vs,
    const float* __restrict__ in1, const float* __restrict__ in2,
    const float* __restrict__ gamma_p, float* __restrict__ out)
{
    __shared__ float accb[8][64][33];   // [ksplit][c][q], reused per qt round
    __shared__ float rsl[8][32];
    __shared__ float invl[32];

    const int bid = blockIdx.x;        // 256 blocks = 8 br x 32 quads
    const int br = bid & 7;            // XCD affinity
    const int qq = bid >> 3;           // quad index 0..31 (128 q-rows)
    const int b = br >> 1, rr = br & 1;
    const int tid = threadIdx.x;
    const int w = tid >> 6;            // wave = key-split 0..7 (512 keys each)
    const int l = tid & 63;
    const int q31 = l & 31, hi = l >> 5;

    const unsigned short* Qb = Qs + (size_t)br * 65536;
    const unsigned short* Kb = Ks + (size_t)br * 65536;
    const unsigned short* Vb = Vs + (size_t)br * 262144;

    // 4 Q B-fragments (q-tiles qq*4 .. +3), held for the whole kernel
    const bf16x8 aq0 = *(const bf16x8*)(Qb + (size_t)(qq * 4 + 0) * 512 + l * 8);
    const bf16x8 aq1 = *(const bf16x8*)(Qb + (size_t)(qq * 4 + 1) * 512 + l * 8);
    const bf16x8 aq2 = *(const bf16x8*)(Qb + (size_t)(qq * 4 + 2) * 512 + l * 8);
    const bf16x8 aq3 = *(const bf16x8*)(Qb + (size_t)(qq * 4 + 3) * 512 + l * 8);

    const f32x16 z16 = {0,0,0,0,0,0,0,0,0,0,0,0,0,0,0,0};
    f32x16 acc00 = z16, acc01 = z16;   // qt0: c0..31 / c32..63
    f32x16 acc10 = z16, acc11 = z16;
    f32x16 acc20 = z16, acc21 = z16;
    f32x16 acc30 = z16, acc31 = z16;
    float rsum0 = 0.f, rsum1 = 0.f, rsum2 = 0.f, rsum3 = 0.f;

    const unsigned short* kbase = Kb + (size_t)(w * 16) * 512 + l * 8;
    const unsigned short* vbase = Vb + (size_t)(w * 16) * 2048 + l * 8;

    bf16x8 kfA = *(const bf16x8*)kbase;
    #pragma unroll 1
    for (int t = 0; t < 16; ++t) {
        // V for current tile: latency covered by QK MFMAs + softmax below
        bf16x8 vf0 = *(const bf16x8*)(vbase);
        bf16x8 vf1 = *(const bf16x8*)(vbase + 512);
        bf16x8 vf2 = *(const bf16x8*)(vbase + 1024);
        bf16x8 vf3 = *(const bf16x8*)(vbase + 1536);
        // K prefetch one tile ahead (last read lands in adjacent ws region; unused)
        bf16x8 kfN = *(const bf16x8*)(kbase + 512);

        SOFTPV(0, acc00, acc01);
        SOFTPV(1, acc10, acc11);
        SOFTPV(2, acc20, acc21);
        SOFTPV(3, acc30, acc31);

        kfA = kfN;
        kbase += 512;
        vbase += 2048;
    }

    const float g = gamma_p[0];
    const float* featp = (rr ? in2 : in1) + (size_t)b * 64 * N_SP;
    float* outp = out + (size_t)rr * (4ull * 64 * N_SP) + (size_t)b * 64 * N_SP;

    EPI(0, acc00, acc01);
    EPI(1, acc10, acc11);
    EPI(2, acc20, acc21);
    EPI(3, acc30, acc31);
}

extern "C" void kernel_launch(void* const* d_in, const int* in_sizes, int n_in,
                              void* d_out, int out_size, void* d_ws, size_t ws_size,
                              hipStream_t stream) {
    const float* in1 = (const float*)d_in[0];
    const float* in2 = (const float*)d_in[1];
    const float* wq1 = (const float*)d_in[2];  const float* bq1 = (const float*)d_in[3];
    const float* wq2 = (const float*)d_in[4];  const float* bq2 = (const float*)d_in[5];
    const float* wq3 = (const float*)d_in[6];  const float* bq3 = (const float*)d_in[7];
    const float* wq4 = (const float*)d_in[8];  const float* bq4 = (const float*)d_in[9];
    const float* wk  = (const float*)d_in[10]; const float* bk  = (const float*)d_in[11];
    const float* wv  = (const float*)d_in[12]; const float* bv  = (const float*)d_in[13];
    const float* wk2 = (const float*)d_in[14]; const float* bk2 = (const float*)d_in[15];
    const float* wv2 = (const float*)d_in[16]; const float* bv2 = (const float*)d_in[17];
    const float* gamma_p = (const float*)d_in[18];

    unsigned short* Qs = (unsigned short*)d_ws;          // 8 * 65536 shorts
    unsigned short* Ks = Qs + (size_t)8 * 65536;         // 8 * 65536 shorts
    unsigned short* Vs = Ks + (size_t)8 * 65536;         // 8 * 262144 shorts

    stage1_kernel<<<dim3(512), 512, 0, stream>>>(in1, in2, wq1, bq1, wq2, bq2,
                                                 wq3, bq3, wq4, bq4, wk, bk, wv, bv,
                                                 wk2, bk2, wv2, bv2, Qs, Ks, Vs);
    attn_kernel<<<dim3(256), 512, 0, stream>>>(Qs, Ks, Vs, in1, in2, gamma_p,
                                               (float*)d_out);
}